// Round 1
// baseline (1120.087 us; speedup 1.0000x reference)
//
#include <hip/hip_runtime.h>
#include <math.h>

#define FIN 512
#define FH 16
#define FOUT 40

// ---------------- CSR build ----------------

__global__ void count_k(const int* __restrict__ dst, int E, int* __restrict__ cnt) {
  int e = blockIdx.x * blockDim.x + threadIdx.x;
  if (e < E) atomicAdd(&cnt[dst[e]], 1);
}

__global__ __launch_bounds__(1024) void scan_k(const int* __restrict__ cnt, int n,
                                               int* __restrict__ off, int* __restrict__ cur,
                                               float* __restrict__ dinv) {
  __shared__ int wsum[16];
  __shared__ int carry_s;
  const int tid = threadIdx.x;
  const int lane = tid & 63, wid = tid >> 6;
  if (tid == 0) carry_s = 0;
  __syncthreads();
  const int CH = 1024 * 8;
  const int nch = (n + CH - 1) / CH;
  for (int c = 0; c < nch; ++c) {
    int base = carry_s;
    int i0 = c * CH + tid * 8;
    int v[8], pre[8];
#pragma unroll
    for (int u = 0; u < 8; ++u) { int i = i0 + u; v[u] = (i < n) ? cnt[i] : 0; }
    int t = 0;
#pragma unroll
    for (int u = 0; u < 8; ++u) { pre[u] = t; t += v[u]; }
    int incl = t;
#pragma unroll
    for (int d = 1; d < 64; d <<= 1) {
      int o = __shfl_up(incl, d);
      if (lane >= d) incl += o;
    }
    if (lane == 63) wsum[wid] = incl;
    __syncthreads();
    int wexcl = 0;
#pragma unroll
    for (int w = 0; w < 16; ++w) if (w < wid) wexcl += wsum[w];
    int texcl = base + wexcl + (incl - t);
#pragma unroll
    for (int u = 0; u < 8; ++u) {
      int i = i0 + u;
      if (i < n) {
        int o = texcl + pre[u];
        off[i] = o; cur[i] = o;
        dinv[i] = rsqrtf((float)v[u] + 1.0f);
      }
    }
    __syncthreads();
    if (tid == 1023) carry_s = base + wexcl + incl;
    __syncthreads();
  }
  if (tid == 0) off[n] = carry_s;
}

__global__ void scatter_k(const int* __restrict__ src, const int* __restrict__ dst, int E,
                          int* __restrict__ cur, int* __restrict__ ssrc) {
  int e = blockIdx.x * blockDim.x + threadIdx.x;
  if (e < E) {
    int p = atomicAdd(&cur[dst[e]], 1);
    ssrc[p] = src[e];
  }
}

// ---------------- h1 = x @ W1 ----------------
// block 256 = 16 groups of 16 lanes; each group owns 4 rows; f-dim split across
// the 16 lanes (f0 = it*64 + l*4, float4). W1^T staged in LDS [16][512].
// Cross-lane reduction done via LDS transpose (static indexing only, no
// runtime-indexed register arrays).

__global__ __launch_bounds__(256) void gemm1_k(const float* __restrict__ x,
                                               const float* __restrict__ W1, int n,
                                               float* __restrict__ h1) {
  __shared__ float w1t[16 * 512];           // [k][f]
  __shared__ float s_red[16 * 16 * 17];     // [g][k][l] pad 17
  for (int idx = threadIdx.x; idx < FIN * FH; idx += 256) {
    int f = idx >> 4, k = idx & 15;
    w1t[k * 512 + f] = W1[idx];
  }
  __syncthreads();
  const int l = threadIdx.x & 15;
  const int g = threadIdx.x >> 4;
  const int row0 = blockIdx.x * 64 + g * 4;
  float acc[4][16];
#pragma unroll
  for (int r2 = 0; r2 < 4; ++r2)
#pragma unroll
    for (int k = 0; k < 16; ++k) acc[r2][k] = 0.f;

#pragma unroll
  for (int it = 0; it < 8; ++it) {
    const int f0 = it * 64 + l * 4;
    float4 xv[4];
#pragma unroll
    for (int r2 = 0; r2 < 4; ++r2) {
      int row = row0 + r2;
      if (row < n)
        xv[r2] = *(const float4*)(x + (size_t)row * FIN + f0);
      else
        xv[r2] = make_float4(0.f, 0.f, 0.f, 0.f);
    }
#pragma unroll
    for (int k = 0; k < 16; ++k) {
      float4 w = *(const float4*)(w1t + k * 512 + f0);
#pragma unroll
      for (int r2 = 0; r2 < 4; ++r2) {
        acc[r2][k] += xv[r2].x * w.x + xv[r2].y * w.y + xv[r2].z * w.z + xv[r2].w * w.w;
      }
    }
  }

  const int gg = threadIdx.x >> 4;   // reader group
  const int kk = threadIdx.x & 15;   // reader feature
  for (int r2 = 0; r2 < 4; ++r2) {
    __syncthreads();
#pragma unroll
    for (int k = 0; k < 16; ++k) s_red[(g * 16 + k) * 17 + l] = acc[r2][k];
    __syncthreads();
    float sum = 0.f;
#pragma unroll
    for (int l2 = 0; l2 < 16; ++l2) sum += s_red[(gg * 16 + kk) * 17 + l2];
    int row = blockIdx.x * 64 + gg * 4 + r2;
    if (row < n) h1[(size_t)row * FH + kk] = sum;
  }
}

// ---------------- layer-1 gather: r = relu(dinv_i * sum + b1) ----------------
// one wave per node: lane = esub*16 + k ; 4 edges in flight, 16 features.

__global__ __launch_bounds__(256) void gather1_k(const float* __restrict__ h1,
                                                 const int* __restrict__ off,
                                                 const int* __restrict__ ssrc,
                                                 const float* __restrict__ dinv,
                                                 const float* __restrict__ b1, int n,
                                                 float* __restrict__ r) {
  const int lane = threadIdx.x & 63;
  const int wid = threadIdx.x >> 6;
  const int i = blockIdx.x * 4 + wid;
  if (i >= n) return;
  const int k = lane & 15, esub = lane >> 4;
  const int jb = off[i], je = off[i + 1];
  const float di = dinv[i];
  float acc = 0.f;
  for (int j = jb + esub; j < je; j += 4) {
    int s = ssrc[j];
    acc += h1[(size_t)s * FH + k] * dinv[s];
  }
  if (esub == 0) acc += h1[(size_t)i * FH + k] * di;  // self loop (dinv_i^2 after scale)
  acc += __shfl_xor(acc, 16);
  acc += __shfl_xor(acc, 32);
  if (lane < 16) {
    float v = di * acc + b1[k];
    r[(size_t)i * FH + k] = v > 0.f ? v : 0.f;
  }
}

// ------- layer-2: gather in 16-dim, then W2 matvec + b2 + log_softmax -------

__global__ __launch_bounds__(256) void gather2_k(const float* __restrict__ rbuf,
                                                 const int* __restrict__ off,
                                                 const int* __restrict__ ssrc,
                                                 const float* __restrict__ dinv,
                                                 const float* __restrict__ W2,
                                                 const float* __restrict__ b2, int n,
                                                 float* __restrict__ out) {
  __shared__ float w2s[FH * FOUT + FOUT];  // W2 [16][40] then b2 [40]
  for (int idx = threadIdx.x; idx < FH * FOUT + FOUT; idx += 256)
    w2s[idx] = (idx < FH * FOUT) ? W2[idx] : b2[idx - FH * FOUT];
  __syncthreads();

  const int lane = threadIdx.x & 63;
  const int wid = threadIdx.x >> 6;
  const int i = blockIdx.x * 4 + wid;
  if (i >= n) return;
  const int k = lane & 15, esub = lane >> 4;
  const int jb = off[i], je = off[i + 1];
  const float di = dinv[i];
  float acc = 0.f;
  for (int j = jb + esub; j < je; j += 4) {
    int s = ssrc[j];
    acc += rbuf[(size_t)s * FH + k] * dinv[s];
  }
  if (esub == 0) acc += rbuf[(size_t)i * FH + k] * di;
  acc += __shfl_xor(acc, 16);
  acc += __shfl_xor(acc, 32);
  acc *= di;  // every lane now holds agg16[k] for k = lane&15

  float hv = (lane < FOUT) ? w2s[FH * FOUT + lane] : 0.f;
#pragma unroll
  for (int kk = 0; kk < 16; ++kk) {
    float a = __shfl(acc, kk);  // lane kk holds agg16[kk]
    if (lane < FOUT) hv += a * w2s[kk * FOUT + lane];
  }

  // log_softmax over the 40 valid lanes
  float m = (lane < FOUT) ? hv : -INFINITY;
#pragma unroll
  for (int d = 1; d < 64; d <<= 1) m = fmaxf(m, __shfl_xor(m, d));
  float ex = (lane < FOUT) ? expf(hv - m) : 0.f;
#pragma unroll
  for (int d = 1; d < 64; d <<= 1) ex += __shfl_xor(ex, d);
  if (lane < FOUT) out[(size_t)i * FOUT + lane] = hv - m - logf(ex);
}

// ---------------- launch ----------------

extern "C" void kernel_launch(void* const* d_in, const int* in_sizes, int n_in,
                              void* d_out, int out_size, void* d_ws, size_t ws_size,
                              hipStream_t stream) {
  const float* x  = (const float*)d_in[0];
  const int*   ei = (const int*)d_in[1];
  const float* W1 = (const float*)d_in[2];
  const float* b1 = (const float*)d_in[3];
  const float* W2 = (const float*)d_in[4];
  const float* b2 = (const float*)d_in[5];
  float* out = (float*)d_out;

  const int n = in_sizes[0] / FIN;
  const int E = in_sizes[1] / 2;
  const int* src = ei;
  const int* dst = ei + E;

  char* ws = (char*)d_ws;
  size_t o = 0;
  auto alloc = [&](size_t bytes) {
    void* p = ws + o;
    o = (o + bytes + 255) & ~(size_t)255;
    return p;
  };
  int*   cnt  = (int*)alloc((size_t)n * 4);
  int*   off  = (int*)alloc((size_t)(n + 1) * 4);
  int*   cur  = (int*)alloc((size_t)n * 4);
  float* dinv = (float*)alloc((size_t)n * 4);
  int*   ssrc = (int*)alloc((size_t)E * 4);
  float* h1   = (float*)alloc((size_t)n * FH * 4);
  float* rb   = (float*)alloc((size_t)n * FH * 4);

  hipMemsetAsync(cnt, 0, (size_t)n * 4, stream);

  int egrid = (E + 255) / 256;
  count_k<<<egrid, 256, 0, stream>>>(dst, E, cnt);
  scan_k<<<1, 1024, 0, stream>>>(cnt, n, off, cur, dinv);
  scatter_k<<<egrid, 256, 0, stream>>>(src, dst, E, cur, ssrc);

  gemm1_k<<<(n + 63) / 64, 256, 0, stream>>>(x, W1, n, h1);
  gather1_k<<<(n + 3) / 4, 256, 0, stream>>>(h1, off, ssrc, dinv, b1, n, rb);
  gather2_k<<<(n + 3) / 4, 256, 0, stream>>>(rb, off, ssrc, dinv, W2, b2, n, out);
}

// Round 2
// 804.959 us; speedup vs baseline: 1.3915x; 1.3915x over previous
//
#include <hip/hip_runtime.h>
#include <math.h>

#define FIN 512
#define FH 16
#define FOUT 40

// ---------------- CSR build ----------------

__global__ void count_k(const int* __restrict__ dst, int E, int* __restrict__ cnt) {
  int e = blockIdx.x * blockDim.x + threadIdx.x;
  if (e < E) atomicAdd(&cnt[dst[e]], 1);
}

__global__ __launch_bounds__(1024) void scan_k(const int* __restrict__ cnt, int n,
                                               int* __restrict__ off, int* __restrict__ cur,
                                               float* __restrict__ dinv) {
  __shared__ int wsum[16];
  __shared__ int carry_s;
  const int tid = threadIdx.x;
  const int lane = tid & 63, wid = tid >> 6;
  if (tid == 0) carry_s = 0;
  __syncthreads();
  const int CH = 1024 * 8;
  const int nch = (n + CH - 1) / CH;
  for (int c = 0; c < nch; ++c) {
    int base = carry_s;
    int i0 = c * CH + tid * 8;
    int v[8], pre[8];
#pragma unroll
    for (int u = 0; u < 8; ++u) { int i = i0 + u; v[u] = (i < n) ? cnt[i] : 0; }
    int t = 0;
#pragma unroll
    for (int u = 0; u < 8; ++u) { pre[u] = t; t += v[u]; }
    int incl = t;
#pragma unroll
    for (int d = 1; d < 64; d <<= 1) {
      int o = __shfl_up(incl, d);
      if (lane >= d) incl += o;
    }
    if (lane == 63) wsum[wid] = incl;
    __syncthreads();
    int wexcl = 0;
#pragma unroll
    for (int w = 0; w < 16; ++w) if (w < wid) wexcl += wsum[w];
    int texcl = base + wexcl + (incl - t);
#pragma unroll
    for (int u = 0; u < 8; ++u) {
      int i = i0 + u;
      if (i < n) {
        int o = texcl + pre[u];
        off[i] = o; cur[i] = o;
        dinv[i] = rsqrtf((float)v[u] + 1.0f);
      }
    }
    __syncthreads();
    if (tid == 1023) carry_s = base + wexcl + incl;
    __syncthreads();
  }
  if (tid == 0) off[n] = carry_s;
}

__global__ void scatter_k(const int* __restrict__ src, const int* __restrict__ dst, int E,
                          int* __restrict__ cur, int* __restrict__ ssrc) {
  int e = blockIdx.x * blockDim.x + threadIdx.x;
  if (e < E) {
    int p = atomicAdd(&cur[dst[e]], 1);
    ssrc[p] = src[e];
  }
}

// ---------------- hs1 = (x @ W1) * dinv[row] ----------------
// Thread-per-row GEMV. W1 (32 KiB) staged in LDS, read at wave-uniform
// addresses (broadcast, conflict-free). acc = 16 floats (4x float4).
// VGPR ~48 -> high occupancy; each thread streams its row as float4.

__global__ __launch_bounds__(256) void gemm1_k(const float* __restrict__ x,
                                               const float* __restrict__ W1,
                                               const float* __restrict__ dinv, int n,
                                               float* __restrict__ hs1) {
  __shared__ float w1s[FIN * FH];  // [f][k] as given, 32 KiB
  for (int idx = threadIdx.x; idx < FIN * FH; idx += 256) w1s[idx] = W1[idx];
  __syncthreads();

  const int row_raw = blockIdx.x * 256 + threadIdx.x;
  const int row = row_raw < n ? row_raw : n - 1;  // tail threads compute garbage, no store
  const float4* __restrict__ xr = (const float4*)(x + (size_t)row * FIN);

  float4 a0 = {0, 0, 0, 0}, a1 = {0, 0, 0, 0}, a2 = {0, 0, 0, 0}, a3 = {0, 0, 0, 0};

#pragma unroll 2
  for (int it = 0; it < FIN / 4; ++it) {
    float4 xv = xr[it];
    const float* wf = w1s + it * 4 * FH;
#pragma unroll
    for (int j = 0; j < 4; ++j) {
      const float xj = (j == 0) ? xv.x : (j == 1) ? xv.y : (j == 2) ? xv.z : xv.w;
      const float* wj = wf + j * FH;
      float4 w0 = *(const float4*)(wj + 0);
      float4 w1 = *(const float4*)(wj + 4);
      float4 w2 = *(const float4*)(wj + 8);
      float4 w3 = *(const float4*)(wj + 12);
      a0.x += xj * w0.x; a0.y += xj * w0.y; a0.z += xj * w0.z; a0.w += xj * w0.w;
      a1.x += xj * w1.x; a1.y += xj * w1.y; a1.z += xj * w1.z; a1.w += xj * w1.w;
      a2.x += xj * w2.x; a2.y += xj * w2.y; a2.z += xj * w2.z; a2.w += xj * w2.w;
      a3.x += xj * w3.x; a3.y += xj * w3.y; a3.z += xj * w3.z; a3.w += xj * w3.w;
    }
  }

  if (row_raw < n) {
    const float di = dinv[row];
    float4* o = (float4*)(hs1 + (size_t)row * FH);
    a0.x *= di; a0.y *= di; a0.z *= di; a0.w *= di;
    a1.x *= di; a1.y *= di; a1.z *= di; a1.w *= di;
    a2.x *= di; a2.y *= di; a2.z *= di; a2.w *= di;
    a3.x *= di; a3.y *= di; a3.z *= di; a3.w *= di;
    o[0] = a0; o[1] = a1; o[2] = a2; o[3] = a3;
  }
}

// ---------------- layer-1 gather ----------------
// hs1 already carries dinv[src]; rs output carries dinv[i] for layer 2.
// One wave per node: lane = esub*16 + k; 4 edges in flight; 2-deep pipeline
// (next ssrc load overlaps current feature load).

__global__ __launch_bounds__(256) void gather1_k(const float* __restrict__ hs1,
                                                 const int* __restrict__ off,
                                                 const int* __restrict__ ssrc,
                                                 const float* __restrict__ dinv,
                                                 const float* __restrict__ b1, int n,
                                                 float* __restrict__ rs) {
  const int lane = threadIdx.x & 63;
  const int wid = threadIdx.x >> 6;
  const int i = blockIdx.x * 4 + wid;
  if (i >= n) return;
  const int k = lane & 15, esub = lane >> 4;
  const int jb = off[i], je = off[i + 1];
  float acc = 0.f;
  int j = jb + esub;
  int s = (j < je) ? ssrc[j] : -1;
  while (s >= 0) {
    const int j2 = j + 4;
    const int s2 = (j2 < je) ? ssrc[j2] : -1;
    acc += hs1[(size_t)s * FH + k];
    j = j2; s = s2;
  }
  if (esub == 0) acc += hs1[(size_t)i * FH + k];  // self loop
  acc += __shfl_xor(acc, 16);
  acc += __shfl_xor(acc, 32);
  if (lane < 16) {
    const float di = dinv[i];
    float v = di * acc + b1[k];
    rs[(size_t)i * FH + k] = (v > 0.f ? v : 0.f) * di;
  }
}

// ------- layer-2: gather in 16-dim, then W2 matvec + b2 + log_softmax -------

__global__ __launch_bounds__(256) void gather2_k(const float* __restrict__ rs,
                                                 const int* __restrict__ off,
                                                 const int* __restrict__ ssrc,
                                                 const float* __restrict__ dinv,
                                                 const float* __restrict__ W2,
                                                 const float* __restrict__ b2, int n,
                                                 float* __restrict__ out) {
  __shared__ float w2s[FH * FOUT + FOUT];  // W2 [16][40] then b2 [40]
  for (int idx = threadIdx.x; idx < FH * FOUT + FOUT; idx += 256)
    w2s[idx] = (idx < FH * FOUT) ? W2[idx] : b2[idx - FH * FOUT];
  __syncthreads();

  const int lane = threadIdx.x & 63;
  const int wid = threadIdx.x >> 6;
  const int i = blockIdx.x * 4 + wid;
  if (i >= n) return;
  const int k = lane & 15, esub = lane >> 4;
  const int jb = off[i], je = off[i + 1];
  float acc = 0.f;
  int j = jb + esub;
  int s = (j < je) ? ssrc[j] : -1;
  while (s >= 0) {
    const int j2 = j + 4;
    const int s2 = (j2 < je) ? ssrc[j2] : -1;
    acc += rs[(size_t)s * FH + k];
    j = j2; s = s2;
  }
  if (esub == 0) acc += rs[(size_t)i * FH + k];  // self loop
  acc += __shfl_xor(acc, 16);
  acc += __shfl_xor(acc, 32);
  acc *= dinv[i];  // every lane now holds agg16[k] for k = lane&15

  float hv = (lane < FOUT) ? w2s[FH * FOUT + lane] : 0.f;
#pragma unroll
  for (int kk = 0; kk < 16; ++kk) {
    const float a = __shfl(acc, kk);  // lane kk holds agg16[kk]
    if (lane < FOUT) hv += a * w2s[kk * FOUT + lane];
  }

  // log_softmax over the 40 valid lanes
  float m = (lane < FOUT) ? hv : -INFINITY;
#pragma unroll
  for (int d = 1; d < 64; d <<= 1) m = fmaxf(m, __shfl_xor(m, d));
  float ex = (lane < FOUT) ? expf(hv - m) : 0.f;
#pragma unroll
  for (int d = 1; d < 64; d <<= 1) ex += __shfl_xor(ex, d);
  if (lane < FOUT) out[(size_t)i * FOUT + lane] = hv - m - logf(ex);
}

// ---------------- launch ----------------

extern "C" void kernel_launch(void* const* d_in, const int* in_sizes, int n_in,
                              void* d_out, int out_size, void* d_ws, size_t ws_size,
                              hipStream_t stream) {
  const float* x  = (const float*)d_in[0];
  const int*   ei = (const int*)d_in[1];
  const float* W1 = (const float*)d_in[2];
  const float* b1 = (const float*)d_in[3];
  const float* W2 = (const float*)d_in[4];
  const float* b2 = (const float*)d_in[5];
  float* out = (float*)d_out;

  const int n = in_sizes[0] / FIN;
  const int E = in_sizes[1] / 2;
  const int* src = ei;
  const int* dst = ei + E;

  char* ws = (char*)d_ws;
  size_t o = 0;
  auto alloc = [&](size_t bytes) {
    void* p = ws + o;
    o = (o + bytes + 255) & ~(size_t)255;
    return p;
  };
  int*   cnt  = (int*)alloc((size_t)n * 4);
  int*   off  = (int*)alloc((size_t)(n + 1) * 4);
  int*   cur  = (int*)alloc((size_t)n * 4);
  float* dinv = (float*)alloc((size_t)n * 4);
  int*   ssrc = (int*)alloc((size_t)E * 4);
  float* hs1  = (float*)alloc((size_t)n * FH * 4);
  float* rsb  = (float*)alloc((size_t)n * FH * 4);

  hipMemsetAsync(cnt, 0, (size_t)n * 4, stream);

  int egrid = (E + 255) / 256;
  count_k<<<egrid, 256, 0, stream>>>(dst, E, cnt);
  scan_k<<<1, 1024, 0, stream>>>(cnt, n, off, cur, dinv);
  scatter_k<<<egrid, 256, 0, stream>>>(src, dst, E, cur, ssrc);

  gemm1_k<<<(n + 255) / 256, 256, 0, stream>>>(x, W1, dinv, n, hs1);
  gather1_k<<<(n + 3) / 4, 256, 0, stream>>>(hs1, off, ssrc, dinv, b1, n, rsb);
  gather2_k<<<(n + 3) / 4, 256, 0, stream>>>(rsb, off, ssrc, dinv, W2, b2, n, out);
}